// Round 1
// baseline (8380.560 us; speedup 1.0000x reference)
//
#include <hip/hip_runtime.h>
#include <hip/hip_bf16.h>

// TT-LSTM: B=32,T=1024,I=512,H=1024,R=16,G=4H=4096.
// Strategy: rank-16 factorization kept un-materialized.
//   xu = x @ U_ih           (prologue kernel, (B*T,512)@(512,16), memory-bound)
//   per step: z = h @ U_hh (distributed partials), gates = [xu_t|z] @ [V_ih;V_hh] + b
// Persistent cooperative-style kernel, 64 blocks x 512 threads, 1 grid barrier/step.

#define B_ 32
#define T_ 1024
#define I_ 512
#define H_ 1024
#define R_ 16
#define G_ 4096
#define NB 64        // scan blocks
#define HC 16        // h-cols per block = H_/NB
#define SCAN_T 512   // 32 batch x 16 cols

__device__ __forceinline__ float fsig(float x) {
  return __builtin_amdgcn_rcpf(1.f + __expf(-x));
}
__device__ __forceinline__ float ftanh_(float x) {
  return 2.f * __builtin_amdgcn_rcpf(1.f + __expf(-2.f * x)) - 1.f;
}

// Grid barrier: monotonically increasing counter in workspace (zeroed per launch).
// Release fence publishes this block's stores (incl. cross-XCD L2 writeback);
// acquire fence after spin invalidates stale L1/L2 before reading partials.
__device__ __forceinline__ void grid_barrier(unsigned* cnt, unsigned target) {
  __syncthreads();                 // all stores of this block issued (+vmcnt drain)
  if (threadIdx.x == 0) {
    __threadfence();               // release (agent scope)
    __hip_atomic_fetch_add(cnt, 1u, __ATOMIC_RELAXED, __HIP_MEMORY_SCOPE_AGENT);
    while (__hip_atomic_load(cnt, __ATOMIC_RELAXED, __HIP_MEMORY_SCOPE_AGENT) < target) {
      __builtin_amdgcn_s_sleep(2);
    }
    __threadfence();               // acquire
  }
  __syncthreads();
}

// xu[t][b][r] = sum_i x[b][t][i] * U_ih[i][r]
__global__ void k_xu(const float* __restrict__ x, const float* __restrict__ u,
                     float* __restrict__ xu) {
  __shared__ float U[I_ * R_];     // 32 KB
  for (int i = threadIdx.x; i < I_ * R_; i += 256) U[i] = u[i];
  __syncthreads();
  unsigned gid = blockIdx.x * 256 + threadIdx.x;
  int r = gid & 15;
  unsigned row = gid >> 4;                 // b*T_ + t
  unsigned b = row >> 10, t = row & 1023;
  const float* xr = x + (size_t)row * I_;
  float acc = 0.f;
#pragma unroll 8
  for (int k = 0; k < I_; k += 4) {
    float4 xv = *(const float4*)(xr + k);
    acc += xv.x * U[(k + 0) * R_ + r];
    acc += xv.y * U[(k + 1) * R_ + r];
    acc += xv.z * U[(k + 2) * R_ + r];
    acc += xv.w * U[(k + 3) * R_ + r];
  }
  xu[(size_t)t * (B_ * R_) + b * R_ + r] = acc;
}

__global__ __launch_bounds__(SCAN_T) void k_scan(
    const float* __restrict__ wih1, const float* __restrict__ whh0,
    const float* __restrict__ whh1, const float* __restrict__ bih,
    const float* __restrict__ bhh, const float* __restrict__ xu,
    float* __restrict__ part, unsigned* __restrict__ cnt,
    float* __restrict__ out) {
  const int tid = threadIdx.x;
  const int blk = blockIdx.x;
  const int b = tid & 31;          // batch row
  const int j = tid >> 5;          // 0..15: local h-col, reused as r for z

  __shared__ float Vc[32][4][HC];  // [k][gate][j]  rows 0-15=V_ih, 16-31=V_hh (8 KB)
  __shared__ float bias[4][HC];
  __shared__ float Ul[HC][R_];     // U_hh rows for owned h-cols (1 KB)
  __shared__ float cat[B_][33];    // [b][k] (k<16: xu_t, k>=16: z), padded
  __shared__ float hl[HC][36];     // h local [j][b], padded for conflict-free remap

  for (int i = tid; i < 32 * 4 * HC; i += SCAN_T) {
    int k = i >> 6; int rem = i & 63;
    int gg = rem >> 4, jj = rem & 15;
    int col = gg * H_ + blk * HC + jj;
    Vc[k][gg][jj] = (k < R_) ? wih1[k * G_ + col] : whh1[(k - R_) * G_ + col];
  }
  if (tid < 64) {
    int gg = tid >> 4, jj = tid & 15;
    int col = gg * H_ + blk * HC + jj;
    bias[gg][jj] = bih[col] + bhh[col];
  }
  if (tid < HC * R_) {
    int jj = tid >> 4, r = tid & 15;
    Ul[jj][r] = whh0[(blk * HC + jj) * R_ + r];
  }
  // zero this block's slice of partials buffer 0 (h0 == 0)
  part[blk * 512 + tid] = 0.f;

  float c = 0.f;
  unsigned phase = 1;
  grid_barrier(cnt, NB * phase); phase++;

  int p = 0;
  for (int t = 0; t < T_; ++t) {
    // stage xu_t (coalesced 2 KB)
    cat[tid >> 4][tid & 15] = xu[(size_t)t * (B_ * R_) + tid];

    // z[b][j] = sum over all blocks' partials (64 independent loads, unrolled)
    const float* pb = part + p * (NB * 512) + (j * 32 + b);
    float v[NB];
#pragma unroll
    for (int u_ = 0; u_ < NB; ++u_) v[u_] = pb[(size_t)u_ * 512];
    float z = 0.f;
#pragma unroll
    for (int u_ = 0; u_ < NB; ++u_) z += v[u_];
    cat[b][16 + j] = z;
    __syncthreads();

    // gates for (b, h-col j): 4 dots of K=32
    float d0 = bias[0][j], d1 = bias[1][j], d2 = bias[2][j], d3 = bias[3][j];
#pragma unroll
    for (int k = 0; k < 32; ++k) {
      float cv = cat[b][k];
      d0 += cv * Vc[k][0][j];
      d1 += cv * Vc[k][1][j];
      d2 += cv * Vc[k][2][j];
      d3 += cv * Vc[k][3][j];
    }
    float ig = fsig(d0), fg = fsig(d1), g2 = ftanh_(d2), og = fsig(d3);
    c = fg * c + ig * g2;
    float h = og * ftanh_(c);
    hl[j][b] = h;
    __syncthreads();

    // hidden_seq write (remapped for 64B-contiguous chunks)
    {
      int b2 = tid >> 4, j2 = tid & 15;
      out[(size_t)b2 * (T_ * H_) + (size_t)t * H_ + blk * HC + j2] = hl[j2][b2];
    }

    // z-partial for next step: zp[b][r] = sum_j h[j][b] * U[j][r]
    float zp = 0.f;
#pragma unroll
    for (int jj = 0; jj < HC; ++jj) zp += hl[jj][b] * Ul[jj][j];
    part[(p ^ 1) * (NB * 512) + blk * 512 + tid] = zp;

    grid_barrier(cnt, NB * phase); phase++;
    p ^= 1;
  }

  // h_n and c_n
  {
    int b2 = tid >> 4, j2 = tid & 15;
    out[(size_t)(B_ * T_ * H_) + (size_t)b2 * H_ + blk * HC + j2] = hl[j2][b2];
  }
  out[(size_t)(B_ * T_ * H_) + B_ * H_ + (size_t)b * H_ + blk * HC + j] = c;
}

extern "C" void kernel_launch(void* const* d_in, const int* in_sizes, int n_in,
                              void* d_out, int out_size, void* d_ws, size_t ws_size,
                              hipStream_t stream) {
  const float* x    = (const float*)d_in[0];
  const float* wih0 = (const float*)d_in[1];   // (1,I,R)  -> U_ih[i][r]
  const float* wih1 = (const float*)d_in[2];   // (R,G,1)  -> V_ih[r][n]
  const float* whh0 = (const float*)d_in[3];   // (1,H,R)  -> U_hh[j][r]
  const float* whh1 = (const float*)d_in[4];   // (R,G,1)  -> V_hh[r][n]
  const float* bih  = (const float*)d_in[5];
  const float* bhh  = (const float*)d_in[6];
  float* out = (float*)d_out;

  unsigned char* ws = (unsigned char*)d_ws;
  unsigned* cnt = (unsigned*)ws;                                  // 4 KB reserved
  float* xu   = (float*)(ws + 4096);                              // 2 MB
  float* part = (float*)(ws + 4096 + (size_t)T_ * B_ * R_ * 4);   // 256 KB (2 bufs)

  hipMemsetAsync(cnt, 0, 256, stream);
  k_xu<<<(B_ * T_ * R_) / 256, 256, 0, stream>>>(x, wih0, xu);
  k_scan<<<NB, SCAN_T, 0, stream>>>(wih1, whh0, whh1, bih, bhh, xu, part, cnt, out);
}

// Round 2
// 5206.170 us; speedup vs baseline: 1.6097x; 1.6097x over previous
//
#include <hip/hip_runtime.h>
#include <hip/hip_bf16.h>

// TT-LSTM B=32,T=1024,I=512,H=1024,R=16,G=4096.
// Round 2: weights in VGPRs (128/thread), NB=32 persistent blocks,
// flag-based producer/consumer sync (no central barrier), double-buffered
// rank-16 partials (2 KB/block/step cross-block traffic).

#define B_ 32
#define T_ 1024
#define I_ 512
#define H_ 1024
#define R_ 16
#define G_ 4096
#define NB 32        // scan blocks
#define HC 32        // h-cols per block = H_/NB
#define SCAN_T 512

__device__ __forceinline__ float fsig(float x) {
  return __builtin_amdgcn_rcpf(1.f + __expf(-x));
}
__device__ __forceinline__ float ftanh_(float x) {
  return 2.f * __builtin_amdgcn_rcpf(1.f + __expf(-2.f * x)) - 1.f;
}

// xu[t][b][r] = sum_i x[b][t][i] * U_ih[i][r]; 1 row/thread, 16 accs in regs.
__global__ __launch_bounds__(128) void k_xu(const float* __restrict__ x,
                                            const float* __restrict__ u,
                                            float* __restrict__ xu) {
  __shared__ float U[I_][R_];  // 32 KB
  for (int i = threadIdx.x; i < I_ * R_; i += 128) ((float*)U)[i] = u[i];
  __syncthreads();
  int row = blockIdx.x * 128 + threadIdx.x;  // b*T_ + t
  int b = row >> 10, t = row & 1023;
  const float* xr = x + (size_t)row * I_;
  float acc[R_];
#pragma unroll
  for (int r = 0; r < R_; ++r) acc[r] = 0.f;
  for (int k = 0; k < I_; k += 4) {
    float4 xv = *(const float4*)(xr + k);
    float xs[4] = {xv.x, xv.y, xv.z, xv.w};
#pragma unroll
    for (int e = 0; e < 4; ++e)
#pragma unroll
      for (int r = 0; r < R_; ++r) acc[r] += xs[e] * U[k + e][r];
  }
  float* o = xu + ((size_t)t * B_ + b) * R_;
#pragma unroll
  for (int r = 0; r < R_; r += 4)
    *(float4*)(o + r) = make_float4(acc[r], acc[r + 1], acc[r + 2], acc[r + 3]);
}

__global__ __launch_bounds__(SCAN_T, 2) void k_scan(
    const float* __restrict__ wih1, const float* __restrict__ whh0,
    const float* __restrict__ whh1, const float* __restrict__ bih,
    const float* __restrict__ bhh, const float* __restrict__ xu,
    float* __restrict__ part, unsigned* __restrict__ flags,
    float* __restrict__ out) {
  const int tid = threadIdx.x;
  const int blk = blockIdx.x;
  // gate-compute mapping: thread = (col cl, batch pair bh / bh+16)
  const int cl = tid & 31;
  const int bh = tid >> 5;          // 0..15
  const int col = blk * HC + cl;
  // z mapping: thread = (batch bz, rank rz)
  const int bz = tid & 31;
  const int rz = tid >> 5;          // 0..15

  __shared__ float cat[B_][36];     // [b][k]: k<16 xu_t, k>=16 z   (pad->16B align)
  __shared__ float hl[HC][33];      // h local [col][b]
  __shared__ float Ul[HC][17];      // U_hh rows for owned cols

  // ---- loop-invariant weights into registers (128 VGPR) ----
  float w_[4][32];
#pragma unroll
  for (int k = 0; k < R_; ++k)
#pragma unroll
    for (int g = 0; g < 4; ++g) {
      w_[g][k]      = wih1[(size_t)k * G_ + g * H_ + col];
      w_[g][R_ + k] = whh1[(size_t)k * G_ + g * H_ + col];
    }
  float bsum[4];
#pragma unroll
  for (int g = 0; g < 4; ++g) bsum[g] = bih[g * H_ + col] + bhh[g * H_ + col];
  {
    int j = tid >> 4, r = tid & 15;
    Ul[j][r] = whh0[(blk * HC + j) * R_ + r];
  }
  __syncthreads();

  float c0 = 0.f, c1 = 0.f;
  float h0v = 0.f, h1v = 0.f;

  for (int t = 0; t < T_; ++t) {
    const int p = t & 1;
    // ---- Phase A: wait until every block published partials P_t ----
    if (tid < NB) {
      if (tid != blk) {
        while (__hip_atomic_load(&flags[tid * 16], __ATOMIC_RELAXED,
                                 __HIP_MEMORY_SCOPE_AGENT) < (unsigned)t)
          __builtin_amdgcn_s_sleep(1);
      }
      __threadfence();  // acquire: invalidate stale L1/L2 lines
    }
    // stage xu_t (overlaps with wave0's polling)
    cat[tid >> 4][tid & 15] = xu[(size_t)t * (B_ * R_) + tid];
    __syncthreads();

    // ---- Phase B: z[bz][rz] = sum over blocks' partials (32 loads) ----
    {
      const float* pb = part + p * (NB * 512) + tid;
      float z = 0.f;
#pragma unroll
      for (int u = 0; u < NB; ++u) z += pb[u * 512];
      cat[bz][16 + rz] = z;
    }
    __syncthreads();

    // ---- Phase C: gates from registers; K=32 dot per (b, col, gate) ----
    float a0[4], a1[4];
#pragma unroll
    for (int g = 0; g < 4; ++g) { a0[g] = bsum[g]; a1[g] = bsum[g]; }
#pragma unroll
    for (int k = 0; k < 32; k += 4) {
      float4 cv0 = *(const float4*)&cat[bh][k];
      float4 cv1 = *(const float4*)&cat[bh + 16][k];
      float s0[4] = {cv0.x, cv0.y, cv0.z, cv0.w};
      float s1[4] = {cv1.x, cv1.y, cv1.z, cv1.w};
#pragma unroll
      for (int e = 0; e < 4; ++e)
#pragma unroll
        for (int g = 0; g < 4; ++g) {
          a0[g] += s0[e] * w_[g][k + e];
          a1[g] += s1[e] * w_[g][k + e];
        }
    }
    {
      float ig = fsig(a0[0]), fg = fsig(a0[1]), gg = ftanh_(a0[2]), og = fsig(a0[3]);
      c0 = fg * c0 + ig * gg;
      h0v = og * ftanh_(c0);
      ig = fsig(a1[0]); fg = fsig(a1[1]); gg = ftanh_(a1[2]); og = fsig(a1[3]);
      c1 = fg * c1 + ig * gg;
      h1v = og * ftanh_(c1);
    }
    hl[cl][bh] = h0v;
    hl[cl][bh + 16] = h1v;
    out[((size_t)bh * T_ + t) * H_ + col] = h0v;
    out[((size_t)(bh + 16) * T_ + t) * H_ + col] = h1v;
    __syncthreads();

    // ---- Phase D: next-step partial zp[bz][rz] = sum_j h[j][bz]*U[j][rz] ----
    {
      float z2 = 0.f;
#pragma unroll
      for (int j = 0; j < HC; ++j) z2 += hl[j][bz] * Ul[j][rz];
      part[(p ^ 1) * (NB * 512) + blk * 512 + tid] = z2;
    }
    __syncthreads();  // drains vmcnt: partial writes AND this step's reads done
    if (tid == 0) {
      __threadfence();  // release: flush block's stores to coherent point
      __hip_atomic_store(&flags[blk * 16], (unsigned)(t + 1), __ATOMIC_RELAXED,
                         __HIP_MEMORY_SCOPE_AGENT);
    }
  }

  // ---- h_n, c_n ----
  {
    size_t base = (size_t)B_ * T_ * H_;
    out[base + (size_t)bh * H_ + col] = h0v;
    out[base + (size_t)(bh + 16) * H_ + col] = h1v;
    out[base + (size_t)B_ * H_ + (size_t)bh * H_ + col] = c0;
    out[base + (size_t)B_ * H_ + (size_t)(bh + 16) * H_ + col] = c1;
  }
}

extern "C" void kernel_launch(void* const* d_in, const int* in_sizes, int n_in,
                              void* d_out, int out_size, void* d_ws, size_t ws_size,
                              hipStream_t stream) {
  const float* x    = (const float*)d_in[0];
  const float* wih0 = (const float*)d_in[1];  // (1,I,R)
  const float* wih1 = (const float*)d_in[2];  // (R,G,1)
  const float* whh0 = (const float*)d_in[3];  // (1,H,R)
  const float* whh1 = (const float*)d_in[4];  // (R,G,1)
  const float* bih  = (const float*)d_in[5];
  const float* bhh  = (const float*)d_in[6];
  float* out = (float*)d_out;

  unsigned char* ws = (unsigned char*)d_ws;
  unsigned* flags = (unsigned*)ws;                         // 32 x 64B = 2 KB (4 KB rsvd)
  float* part = (float*)(ws + 4096);                       // 2*32*512*4 = 128 KB
  float* xu   = (float*)(ws + 4096 + 2 * NB * 512 * 4);    // 2 MB

  // zero flags + partial buffers (ws is poisoned 0xAA before every launch)
  hipMemsetAsync(ws, 0, 4096 + 2 * NB * 512 * 4, stream);
  k_xu<<<(B_ * T_) / 128, 128, 0, stream>>>(x, wih0, xu);
  k_scan<<<NB, SCAN_T, 0, stream>>>(wih1, whh0, whh1, bih, bhh, xu, part, flags, out);
}